// Round 1
// baseline (999.568 us; speedup 1.0000x reference)
//
#include <hip/hip_runtime.h>
#include <hip/hip_fp16.h>

#define SEQ    2048
#define DIN    2048
#define DOUT   2048
#define NH     32
#define NKV    8
#define HD     64
#define BB     2

typedef _Float16 half_t;
typedef __attribute__((ext_vector_type(8))) _Float16 half8;
typedef __attribute__((ext_vector_type(4))) _Float16 half4;
typedef __attribute__((ext_vector_type(4))) float   floatx4;

// ---------------------------------------------------------------- cast f32->f16
__global__ void cast_f2h(const float* __restrict__ in, half_t* __restrict__ out, int n4) {
    int i = blockIdx.x * blockDim.x + threadIdx.x;
    if (i < n4) {
        float4 v = ((const float4*)in)[i];
        half4 h;
        h[0] = (half_t)v.x; h[1] = (half_t)v.y; h[2] = (half_t)v.z; h[3] = (half_t)v.w;
        ((half4*)out)[i] = h;
    }
}

// ---------------------------------------------------------------- GEMM C(f32) = A(f16,MxK) @ B(f16,KxN)
// block: 256 thr = 4 waves; tile 64x64; wave (wm,wn) does 32x32; BK=32.
__global__ __launch_bounds__(256) void gemm_f16(
    const half_t* __restrict__ A, const half_t* __restrict__ B,
    float* __restrict__ C, int M, int N, int K)
{
    __shared__ half_t Asl[64][40];   // [row][k]   +8 pad
    __shared__ half_t Bsl[64][40];   // [n][k] transposed, +8 pad

    int tid  = threadIdx.x;
    int wave = tid >> 6, lane = tid & 63;
    int quad = lane >> 4, l15 = lane & 15;
    int m0 = blockIdx.y * 64, n0 = blockIdx.x * 64;
    int wm = (wave >> 1) * 32, wn = (wave & 1) * 32;

    floatx4 acc[2][2] = {};

    int ar = tid >> 2;            // A stage: row 0..63
    int ac = (tid & 3) * 8;       //          k col 0,8,16,24
    int bk = tid >> 3;            // B stage: k row 0..31
    int bn = (tid & 7) * 8;       //          n col 0..56

    for (int k0 = 0; k0 < K; k0 += 32) {
        half8 av = *(const half8*)(A + (size_t)(m0 + ar) * K + k0 + ac);
        half8 bv = *(const half8*)(B + (size_t)(k0 + bk) * N + n0 + bn);
        *(half8*)(&Asl[ar][ac]) = av;
        #pragma unroll
        for (int j = 0; j < 8; j++) Bsl[bn + j][bk] = bv[j];
        __syncthreads();

        half8 af0 = *(const half8*)(&Asl[wm + l15][quad * 8]);
        half8 af1 = *(const half8*)(&Asl[wm + 16 + l15][quad * 8]);
        half8 bf0 = *(const half8*)(&Bsl[wn + l15][quad * 8]);
        half8 bf1 = *(const half8*)(&Bsl[wn + 16 + l15][quad * 8]);
        acc[0][0] = __builtin_amdgcn_mfma_f32_16x16x32_f16(af0, bf0, acc[0][0], 0, 0, 0);
        acc[0][1] = __builtin_amdgcn_mfma_f32_16x16x32_f16(af0, bf1, acc[0][1], 0, 0, 0);
        acc[1][0] = __builtin_amdgcn_mfma_f32_16x16x32_f16(af1, bf0, acc[1][0], 0, 0, 0);
        acc[1][1] = __builtin_amdgcn_mfma_f32_16x16x32_f16(af1, bf1, acc[1][1], 0, 0, 0);
        __syncthreads();
    }
    #pragma unroll
    for (int a = 0; a < 2; a++)
        #pragma unroll
        for (int b2 = 0; b2 < 2; b2++)
            #pragma unroll
            for (int r = 0; r < 4; r++) {
                int row = m0 + wm + a * 16 + quad * 4 + r;
                int col = n0 + wn + b2 * 16 + l15;
                C[(size_t)row * N + col] = acc[a][b2][r];
            }
}

// ---------------------------------------------------------------- RoPE, in-place fp32, (b,s,h,d) layout
__global__ void rope_kernel(float* __restrict__ Q, const float* __restrict__ cosb,
                            const float* __restrict__ sinb, int nheads, int total) {
    int idx = blockIdx.x * blockDim.x + threadIdx.x;
    if (idx >= total) return;
    int d = idx & 31;
    int h = (idx >> 5) % nheads;
    int s = (idx / (32 * nheads)) % SEQ;
    int b = idx / (32 * nheads * SEQ);
    size_t base = (((size_t)b * SEQ + s) * nheads + h) * 64;
    float x1 = Q[base + d], x2 = Q[base + d + 32];
    float c1 = cosb[s * 64 + d], c2 = cosb[s * 64 + d + 32];
    float s1 = sinb[s * 64 + d], s2 = sinb[s * 64 + d + 32];
    Q[base + d]      = x1 * c1 - x2 * s1;   // rotated[:32] = -x2
    Q[base + d + 32] = x2 * c2 + x1 * s2;   // rotated[32:] =  x1
}

// ---------------------------------------------------------------- causal GQA flash attention
// block = 256 thr = 4 waves; one (b,h,64-query tile); K-tiles of 32.
__global__ __launch_bounds__(256) void attn_kernel(
    const float* __restrict__ Qf, const float* __restrict__ Kf, const float* __restrict__ Vf,
    half_t* __restrict__ ctx)
{
    __shared__ half_t Ksl[32][72];      // [key][dim]
    __shared__ half_t Vsl[64][40];      // [dim][key]  (V^T)
    __shared__ half_t Psl[4][16][40];   // per-wave P round-trip

    int tid  = threadIdx.x;
    int wave = tid >> 6, lane = tid & 63;
    int quad = lane >> 4, l15 = lane & 15;

    int bid = blockIdx.x;
    int qt  = bid & 31;          // SEQ/64 = 32 q-tiles
    int bh  = bid >> 5;
    int h   = bh & (NH - 1);
    int b   = bh >> 5;
    int g   = h >> 2;            // GROUP_SIZE = 4
    int q0  = qt * 64;

    // Q fragments (load once, fp32 -> fp16)
    int qrow = q0 + wave * 16 + l15;
    half8 qf[2];
    {
        const float* qp = Qf + (((size_t)b * SEQ + qrow) * NH + h) * 64;
        #pragma unroll
        for (int t = 0; t < 2; t++) {
            float4 v0 = *(const float4*)(qp + t * 32 + quad * 8);
            float4 v1 = *(const float4*)(qp + t * 32 + quad * 8 + 4);
            half8 hv;
            hv[0] = (half_t)v0.x; hv[1] = (half_t)v0.y; hv[2] = (half_t)v0.z; hv[3] = (half_t)v0.w;
            hv[4] = (half_t)v1.x; hv[5] = (half_t)v1.y; hv[6] = (half_t)v1.z; hv[7] = (half_t)v1.w;
            qf[t] = hv;
        }
    }

    float m_i[4], l_i[4];
    floatx4 o[4] = {};
    #pragma unroll
    for (int r = 0; r < 4; r++) { m_i[r] = -__builtin_inff(); l_i[r] = 0.f; }

    int kst = tid >> 3;          // staging: key 0..31
    int kdc = (tid & 7) * 8;     //          dim 0..56

    int ntiles = q0 / 32 + 2;
    for (int kt = 0; kt < ntiles; kt++) {
        int kbase = kt * 32;
        {   // stage K (row-major) and V^T, fp32 -> fp16
            size_t off = (((size_t)b * SEQ + kbase + kst) * NKV + g) * 64 + kdc;
            float4 a0 = *(const float4*)(Kf + off);
            float4 a1 = *(const float4*)(Kf + off + 4);
            half8 kv;
            kv[0] = (half_t)a0.x; kv[1] = (half_t)a0.y; kv[2] = (half_t)a0.z; kv[3] = (half_t)a0.w;
            kv[4] = (half_t)a1.x; kv[5] = (half_t)a1.y; kv[6] = (half_t)a1.z; kv[7] = (half_t)a1.w;
            *(half8*)(&Ksl[kst][kdc]) = kv;
            float4 b0 = *(const float4*)(Vf + off);
            float4 b1 = *(const float4*)(Vf + off + 4);
            Vsl[kdc + 0][kst] = (half_t)b0.x; Vsl[kdc + 1][kst] = (half_t)b0.y;
            Vsl[kdc + 2][kst] = (half_t)b0.z; Vsl[kdc + 3][kst] = (half_t)b0.w;
            Vsl[kdc + 4][kst] = (half_t)b1.x; Vsl[kdc + 5][kst] = (half_t)b1.y;
            Vsl[kdc + 6][kst] = (half_t)b1.z; Vsl[kdc + 7][kst] = (half_t)b1.w;
        }
        __syncthreads();

        if (kbase <= q0 + wave * 16 + 15) {   // tile not fully masked for this wave
            floatx4 sa[2] = {};
            #pragma unroll
            for (int hn = 0; hn < 2; hn++)
                #pragma unroll
                for (int t = 0; t < 2; t++) {
                    half8 kf = *(const half8*)(&Ksl[hn * 16 + l15][t * 32 + quad * 8]);
                    sa[hn] = __builtin_amdgcn_mfma_f32_16x16x32_f16(qf[t], kf, sa[hn], 0, 0, 0);
                }

            int row0 = q0 + wave * 16 + quad * 4;
            float val[2][4], mt[4];
            #pragma unroll
            for (int r = 0; r < 4; r++) {
                #pragma unroll
                for (int hn = 0; hn < 2; hn++) {
                    int col = kbase + hn * 16 + l15;
                    val[hn][r] = (col > row0 + r) ? -__builtin_inff() : sa[hn][r] * 0.125f;
                }
                mt[r] = fmaxf(val[0][r], val[1][r]);
                #pragma unroll
                for (int off = 1; off < 16; off <<= 1)
                    mt[r] = fmaxf(mt[r], __shfl_xor(mt[r], off));
            }
            float p[2][4], rs[4];
            #pragma unroll
            for (int r = 0; r < 4; r++) {
                float mn = fmaxf(m_i[r], mt[r]);
                float alpha = __expf(m_i[r] - mn);      // first tile: exp(-inf)=0
                p[0][r] = __expf(val[0][r] - mn);
                p[1][r] = __expf(val[1][r] - mn);
                rs[r] = p[0][r] + p[1][r];
                #pragma unroll
                for (int off = 1; off < 16; off <<= 1)
                    rs[r] += __shfl_xor(rs[r], off);
                l_i[r] = l_i[r] * alpha + rs[r];
                m_i[r] = mn;
                #pragma unroll
                for (int nt = 0; nt < 4; nt++) o[nt][r] *= alpha;
            }
            // P: C-layout -> LDS -> A-layout
            #pragma unroll
            for (int r = 0; r < 4; r++) {
                Psl[wave][quad * 4 + r][l15]      = (half_t)p[0][r];
                Psl[wave][quad * 4 + r][16 + l15] = (half_t)p[1][r];
            }
            half8 pf = *(const half8*)(&Psl[wave][l15][quad * 8]);
            #pragma unroll
            for (int nt = 0; nt < 4; nt++) {
                half8 vfr = *(const half8*)(&Vsl[nt * 16 + l15][quad * 8]);
                o[nt] = __builtin_amdgcn_mfma_f32_16x16x32_f16(pf, vfr, o[nt], 0, 0, 0);
            }
        }
        __syncthreads();
    }

    #pragma unroll
    for (int r = 0; r < 4; r++) {
        float inv = 1.0f / l_i[r];
        int row = q0 + wave * 16 + quad * 4 + r;
        size_t base = ((size_t)b * SEQ + row) * DOUT + h * 64;
        #pragma unroll
        for (int nt = 0; nt < 4; nt++)
            ctx[base + nt * 16 + l15] = (half_t)(o[nt][r] * inv);
    }
}

// ---------------------------------------------------------------- launch
extern "C" void kernel_launch(void* const* d_in, const int* in_sizes, int n_in,
                              void* d_out, int out_size, void* d_ws, size_t ws_size,
                              hipStream_t stream) {
    const float* x    = (const float*)d_in[0];
    const float* cosb = (const float*)d_in[1];
    const float* sinb = (const float*)d_in[2];
    // d_in[3] = mask (causal, computed analytically)
    const float* Wq   = (const float*)d_in[4];
    const float* Wk   = (const float*)d_in[5];
    const float* Wv   = (const float*)d_in[6];
    const float* Wo   = (const float*)d_in[7];
    float* out = (float*)d_out;

    const size_t M   = (size_t)BB * SEQ;       // 4096
    const size_t nX  = M * DIN;                // 8388608
    const size_t nWq = (size_t)DIN * DOUT;     // 4194304
    const size_t nWk = (size_t)DIN * NKV * HD; // 1048576
    const size_t nK  = M * NKV * HD;           // 2097152

    char* ws = (char*)d_ws;
    half_t* xh   = (half_t*)ws;                 ws += nX  * sizeof(half_t);
    half_t* Wqh  = (half_t*)ws;                 ws += nWq * sizeof(half_t);
    half_t* Wkh  = (half_t*)ws;                 ws += nWk * sizeof(half_t);
    half_t* Wvh  = (half_t*)ws;                 ws += nWk * sizeof(half_t);
    half_t* Woh  = (half_t*)ws;                 ws += nWq * sizeof(half_t);
    half_t* ctxh = (half_t*)ws;                 ws += nX  * sizeof(half_t);
    float*  Qf   = (float*)ws;                  ws += nX  * sizeof(float);
    float*  Kf   = (float*)ws;                  ws += nK  * sizeof(float);
    float*  Vf   = (float*)ws;                  ws += nK  * sizeof(float);

    // casts
    cast_f2h<<<(nX  / 4) / 256, 256, 0, stream>>>(x,  xh,  nX / 4);
    cast_f2h<<<(nWq / 4) / 256, 256, 0, stream>>>(Wq, Wqh, nWq / 4);
    cast_f2h<<<(nWk / 4) / 256, 256, 0, stream>>>(Wk, Wkh, nWk / 4);
    cast_f2h<<<(nWk / 4) / 256, 256, 0, stream>>>(Wv, Wvh, nWk / 4);
    cast_f2h<<<(nWq / 4) / 256, 256, 0, stream>>>(Wo, Woh, nWq / 4);

    // projections
    gemm_f16<<<dim3(DOUT / 64, M / 64), 256, 0, stream>>>(xh, Wqh, Qf, M, DOUT, DIN);
    gemm_f16<<<dim3((NKV * HD) / 64, M / 64), 256, 0, stream>>>(xh, Wkh, Kf, M, NKV * HD, DIN);
    gemm_f16<<<dim3((NKV * HD) / 64, M / 64), 256, 0, stream>>>(xh, Wvh, Vf, M, NKV * HD, DIN);

    // RoPE (in place, fp32)
    int totQ = BB * SEQ * NH * 32, totK = BB * SEQ * NKV * 32;
    rope_kernel<<<totQ / 256, 256, 0, stream>>>(Qf, cosb, sinb, NH, totQ);
    rope_kernel<<<totK / 256, 256, 0, stream>>>(Kf, cosb, sinb, NKV, totK);

    // attention -> ctx (fp16, (b,s,h,d))
    attn_kernel<<<BB * NH * (SEQ / 64), 256, 0, stream>>>(Qf, Kf, Vf, ctxh);

    // output projection
    gemm_f16<<<dim3(DOUT / 64, M / 64), 256, 0, stream>>>(ctxh, Woh, out, M, DOUT, DIN);
}

// Round 2
// 619.097 us; speedup vs baseline: 1.6146x; 1.6146x over previous
//
#include <hip/hip_runtime.h>
#include <hip/hip_fp16.h>

#define SEQ    2048
#define DIN    2048
#define DOUT   2048
#define NH     32
#define NKV    8
#define HD     64
#define BB     2

typedef _Float16 half_t;
typedef __attribute__((ext_vector_type(8))) _Float16 half8;
typedef __attribute__((ext_vector_type(4))) _Float16 half4;
typedef __attribute__((ext_vector_type(4))) float   floatx4;

// async 16B global->LDS (wave-uniform LDS base + lane*16)
__device__ __forceinline__ void gload16(void* l, const void* g) {
    __builtin_amdgcn_global_load_lds(
        (const __attribute__((address_space(1))) void*)g,
        (__attribute__((address_space(3))) void*)l, 16, 0, 0);
}

// ---------------------------------------------------------------- cast f32->f16 (layout preserved)
__global__ void cast_f2h(const float* __restrict__ in, half_t* __restrict__ out, int n4) {
    int i = blockIdx.x * blockDim.x + threadIdx.x;
    if (i < n4) {
        float4 v = ((const float4*)in)[i];
        half4 h;
        h[0] = (half_t)v.x; h[1] = (half_t)v.y; h[2] = (half_t)v.z; h[3] = (half_t)v.w;
        ((half4*)out)[i] = h;
    }
}

// ---------------------------------------------------------------- transpose+cast: in f32 [Kd][Nd] -> out f16 [Nd][Kd]
__global__ __launch_bounds__(256) void tcast(const float* __restrict__ in, half_t* __restrict__ out,
                                             int Kd, int Nd) {
    __shared__ float T[32][33];
    int x0 = blockIdx.x * 32;   // N base
    int y0 = blockIdx.y * 32;   // K base
    int tx = threadIdx.x & 31, ty = threadIdx.x >> 5;   // ty 0..7
    #pragma unroll
    for (int j = 0; j < 4; j++)
        T[ty + j * 8][tx] = in[(size_t)(y0 + ty + j * 8) * Nd + x0 + tx];
    __syncthreads();
    #pragma unroll
    for (int j = 0; j < 4; j++)
        out[(size_t)(x0 + ty + j * 8) * Kd + y0 + tx] = (half_t)T[tx][ty + j * 8];
}

// ---------------------------------------------------------------- GEMM C(f32,MxN) = A(f16,MxK) @ Bt(f16,NxK)^T
// m97 structure: 256 thr, tile 128x128, BK=32, global_load_lds, pair-swizzled LDS.
__global__ __launch_bounds__(256) void gemm_tn(
    const half_t* __restrict__ A, const half_t* __restrict__ Bt,
    float* __restrict__ C, int M, int N, int K)
{
    __shared__ half_t As[4096];   // 128 rows x 32 halves, viewed as [64][64] pair-swizzled
    __shared__ half_t Bs[4096];

    int tid = threadIdx.x, wave = tid >> 6, lane = tid & 63;
    int quad = lane >> 4, l15 = lane & 15;
    int m0 = blockIdx.y * 128, n0 = blockIdx.x * 128;
    int wm = (wave >> 1) * 64, wn = (wave & 1) * 64;

    floatx4 acc[4][4] = {};

    // staging: seg s = is*256+tid; phys row p=s>>3, stored col sc=s&7;
    // logical col c = sc ^ (p&7); logical row r = 2p + (c>>2); k-off = (c&3)*8.
    int srow[2], skoff[2], sldso[2];
    #pragma unroll
    for (int is = 0; is < 2; is++) {
        int s = is * 256 + tid;
        int p = s >> 3, sc = s & 7;
        int c = sc ^ (p & 7);
        srow[is]  = 2 * p + (c >> 2);
        skoff[is] = (c & 3) * 8;
        sldso[is] = (is * 256 + wave * 64) * 8;   // wave-uniform, halves
    }

    for (int k0 = 0; k0 < K; k0 += 32) {
        __syncthreads();
        #pragma unroll
        for (int is = 0; is < 2; is++) {
            gload16(&As[sldso[is]], A  + (size_t)(m0 + srow[is]) * K + k0 + skoff[is]);
            gload16(&Bs[sldso[is]], Bt + (size_t)(n0 + srow[is]) * K + k0 + skoff[is]);
        }
        __syncthreads();

        half8 af[4], bf[4];
        #pragma unroll
        for (int i = 0; i < 4; i++) {
            int r  = wm + i * 16 + l15;
            int p  = r >> 1;
            int sc = (((r & 1) * 4 + quad) ^ (p & 7));
            af[i] = *(const half8*)&As[p * 64 + sc * 8];
            int rn  = wn + i * 16 + l15;
            int pn  = rn >> 1;
            int scn = (((rn & 1) * 4 + quad) ^ (pn & 7));
            bf[i] = *(const half8*)&Bs[pn * 64 + scn * 8];
        }
        #pragma unroll
        for (int i = 0; i < 4; i++)
            #pragma unroll
            for (int j = 0; j < 4; j++)
                acc[i][j] = __builtin_amdgcn_mfma_f32_16x16x32_f16(af[i], bf[j], acc[i][j], 0, 0, 0);
    }

    #pragma unroll
    for (int i = 0; i < 4; i++) {
        int row = m0 + wm + i * 16 + quad * 4;
        #pragma unroll
        for (int j = 0; j < 4; j++) {
            int col = n0 + wn + j * 16 + l15;
            #pragma unroll
            for (int r = 0; r < 4; r++)
                C[(size_t)(row + r) * N + col] = acc[i][j][r];
        }
    }
}

// ---------------------------------------------------------------- RoPE + relayout + cast
// Qf f32 [b][s][h*64] -> Qh f16 [b][h][s][64], scaled by 1/8
__global__ void rope_q(const float* __restrict__ Qf, const float* __restrict__ cosb,
                       const float* __restrict__ sinb, half_t* __restrict__ Qh) {
    int idx = blockIdx.x * 256 + threadIdx.x;   // BB*SEQ*NH*32 = 2^22
    int d = idx & 31;
    int h = (idx >> 5) & 31;
    int s = (idx >> 10) & 2047;
    int b = idx >> 21;
    const float* q = Qf + (size_t)(b * 2048 + s) * 2048 + h * 64;
    float x1 = q[d], x2 = q[d + 32];
    float c1 = cosb[s * 64 + d], c2 = cosb[s * 64 + d + 32];
    float s1 = sinb[s * 64 + d], s2 = sinb[s * 64 + d + 32];
    half_t* o = Qh + ((size_t)(b * NH + h) * 2048 + s) * 64;
    o[d]      = (half_t)((x1 * c1 - x2 * s1) * 0.125f);
    o[d + 32] = (half_t)((x2 * c2 + x1 * s2) * 0.125f);
}

// Kf f32 [b][s][g*64] -> Kh f16 [b][g][s][64]
__global__ void rope_k(const float* __restrict__ Kf, const float* __restrict__ cosb,
                       const float* __restrict__ sinb, half_t* __restrict__ Kh) {
    int idx = blockIdx.x * 256 + threadIdx.x;   // BB*SEQ*NKV*32 = 2^20
    int d = idx & 31;
    int g = (idx >> 5) & 7;
    int s = (idx >> 8) & 2047;
    int b = idx >> 19;
    const float* k = Kf + (size_t)(b * 2048 + s) * 512 + g * 64;
    float x1 = k[d], x2 = k[d + 32];
    float c1 = cosb[s * 64 + d], c2 = cosb[s * 64 + d + 32];
    float s1 = sinb[s * 64 + d], s2 = sinb[s * 64 + d + 32];
    half_t* o = Kh + ((size_t)(b * NKV + g) * 2048 + s) * 64;
    o[d]      = (half_t)(x1 * c1 - x2 * s1);
    o[d + 32] = (half_t)(x2 * c2 + x1 * s2);
}

// Vf f32 [b][s][g*64] -> Vt f16 [b][g][64][SEQ]  (V transposed, s fastest)
__global__ __launch_bounds__(256) void v_transpose(const float* __restrict__ Vf, half_t* __restrict__ Vt) {
    __shared__ float T[64][65];
    int s0 = blockIdx.x * 64;
    int bg = blockIdx.y; int b = bg >> 3, g = bg & 7;
    int tx = threadIdx.x & 63, ty = threadIdx.x >> 6;   // ty 0..3
    #pragma unroll
    for (int j = 0; j < 16; j++) {
        int s = ty * 16 + j;
        T[s][tx] = Vf[(size_t)(b * 2048 + s0 + s) * 512 + g * 64 + tx];
    }
    __syncthreads();
    #pragma unroll
    for (int j = 0; j < 16; j++) {
        int d = ty * 16 + j;
        Vt[((size_t)(b * NKV + g) * 64 + d) * SEQ + s0 + tx] = (half_t)T[tx][d];
    }
}

// ---------------------------------------------------------------- causal GQA flash attention
// block 256 = 4 waves; 128 queries/block (32 per wave); K-tiles of 64.
// Qh [b][h][s][64] (pre-scaled), Kh [b][g][s][64], Vt [b][g][d][s]; ctx f16 [b][s][h*64].
__global__ __launch_bounds__(256) void attn(
    const half_t* __restrict__ Qh, const half_t* __restrict__ Kh,
    const half_t* __restrict__ Vt, half_t* __restrict__ ctx)
{
    __shared__ half_t Ks[4096];        // 64 keys x 64 d, 8-seg swizzle
    __shared__ half_t Vs[4096];        // 64 d x 64 keys, 8-seg swizzle
    __shared__ half_t Ps[4][32 * 72];  // per-wave P (32 q x 64 k), stride 72

    int tid = threadIdx.x, wave = tid >> 6, lane = tid & 63;
    int quad = lane >> 4, l15 = lane & 15;
    int bid = blockIdx.x;
    int qt = bid & 15;
    int h  = (bid >> 4) & 31;
    int b  = bid >> 9;
    int g  = h >> 2;
    int q0 = qt * 128;
    int wm = wave * 32;

    // Q fragments (A-layout), loaded once
    half8 qf[2][2];
    {
        const half_t* qp = Qh + (size_t)(b * NH + h) * SEQ * 64;
        #pragma unroll
        for (int mf = 0; mf < 2; mf++) {
            int row = q0 + wm + mf * 16 + l15;
            #pragma unroll
            for (int kc = 0; kc < 2; kc++)
                qf[mf][kc] = *(const half8*)(qp + (size_t)row * 64 + kc * 32 + quad * 8);
        }
    }

    float m_i[2][4], l_i[2][4];
    floatx4 o[2][4] = {};
    #pragma unroll
    for (int mf = 0; mf < 2; mf++)
        #pragma unroll
        for (int r = 0; r < 4; r++) { m_i[mf][r] = -__builtin_inff(); l_i[mf][r] = 0.f; }

    const half_t* kp = Kh + (size_t)(b * NKV + g) * SEQ * 64;
    const half_t* vp = Vt + (size_t)(b * NKV + g) * 64 * SEQ;

    int ntiles = 2 * qt + 2;
    for (int kt = 0; kt < ntiles; kt++) {
        int kb = kt * 64;
        __syncthreads();
        #pragma unroll
        for (int is = 0; is < 2; is++) {
            int s = is * 256 + tid;
            int row = s >> 3, sc = s & 7;
            int c = sc ^ (row & 7);
            int lds = (is * 256 + wave * 64) * 8;   // wave-uniform
            gload16(&Ks[lds], kp + (size_t)(kb + row) * 64 + c * 8);
            gload16(&Vs[lds], vp + (size_t)row * SEQ + kb + c * 8);
        }
        __syncthreads();

        if (kb <= q0 + wm + 31) {
            floatx4 sa[2][4] = {};
            #pragma unroll
            for (int kc = 0; kc < 2; kc++)
                #pragma unroll
                for (int nf = 0; nf < 4; nf++) {
                    int row = nf * 16 + l15;
                    int sc = ((kc * 4 + quad) ^ (row & 7));
                    half8 kf = *(const half8*)&Ks[row * 64 + sc * 8];
                    sa[0][nf] = __builtin_amdgcn_mfma_f32_16x16x32_f16(qf[0][kc], kf, sa[0][nf], 0, 0, 0);
                    sa[1][nf] = __builtin_amdgcn_mfma_f32_16x16x32_f16(qf[1][kc], kf, sa[1][nf], 0, 0, 0);
                }

            bool need_mask = (kb + 63 > q0 + wm);
            half_t* pw = Ps[wave];
            #pragma unroll
            for (int mf = 0; mf < 2; mf++) {
                #pragma unroll
                for (int r = 0; r < 4; r++) {
                    int rowq = q0 + wm + mf * 16 + quad * 4 + r;
                    float vals[4];
                    #pragma unroll
                    for (int nf = 0; nf < 4; nf++) {
                        float v = sa[mf][nf][r];
                        if (need_mask && (kb + nf * 16 + l15 > rowq)) v = -__builtin_inff();
                        vals[nf] = v;
                    }
                    float mt = fmaxf(fmaxf(vals[0], vals[1]), fmaxf(vals[2], vals[3]));
                    #pragma unroll
                    for (int off = 1; off < 16; off <<= 1)
                        mt = fmaxf(mt, __shfl_xor(mt, off));
                    float mn = fmaxf(m_i[mf][r], mt);
                    float alpha = __expf(m_i[mf][r] - mn);
                    m_i[mf][r] = mn;
                    float rs = 0.f;
                    #pragma unroll
                    for (int nf = 0; nf < 4; nf++) {
                        float e = __expf(vals[nf] - mn);
                        rs += e;
                        pw[(mf * 16 + quad * 4 + r) * 72 + nf * 16 + l15] = (half_t)e;
                    }
                    #pragma unroll
                    for (int off = 1; off < 16; off <<= 1)
                        rs += __shfl_xor(rs, off);
                    l_i[mf][r] = l_i[mf][r] * alpha + rs;
                    #pragma unroll
                    for (int nf = 0; nf < 4; nf++) o[mf][nf][r] *= alpha;
                }
            }

            // P (A-layout) and V^T (B-layout) -> PV
            half8 pf[2][2];
            #pragma unroll
            for (int mf = 0; mf < 2; mf++)
                #pragma unroll
                for (int kc = 0; kc < 2; kc++)
                    pf[mf][kc] = *(const half8*)&pw[(mf * 16 + l15) * 72 + kc * 32 + quad * 8];
            #pragma unroll
            for (int kc = 0; kc < 2; kc++)
                #pragma unroll
                for (int nf = 0; nf < 4; nf++) {
                    int row = nf * 16 + l15;
                    int sc = ((kc * 4 + quad) ^ (row & 7));
                    half8 vf = *(const half8*)&Vs[row * 64 + sc * 8];
                    o[0][nf] = __builtin_amdgcn_mfma_f32_16x16x32_f16(pf[0][kc], vf, o[0][nf], 0, 0, 0);
                    o[1][nf] = __builtin_amdgcn_mfma_f32_16x16x32_f16(pf[1][kc], vf, o[1][nf], 0, 0, 0);
                }
        }
    }

    #pragma unroll
    for (int mf = 0; mf < 2; mf++)
        #pragma unroll
        for (int r = 0; r < 4; r++) {
            float inv = 1.0f / l_i[mf][r];
            int row = q0 + wm + mf * 16 + quad * 4 + r;
            size_t base = (size_t)(b * SEQ + row) * DOUT + h * 64;
            #pragma unroll
            for (int nf = 0; nf < 4; nf++)
                ctx[base + nf * 16 + l15] = (half_t)(o[mf][nf][r] * inv);
        }
}

// ---------------------------------------------------------------- launch
extern "C" void kernel_launch(void* const* d_in, const int* in_sizes, int n_in,
                              void* d_out, int out_size, void* d_ws, size_t ws_size,
                              hipStream_t stream) {
    const float* x    = (const float*)d_in[0];
    const float* cosb = (const float*)d_in[1];
    const float* sinb = (const float*)d_in[2];
    const float* Wq   = (const float*)d_in[4];
    const float* Wk   = (const float*)d_in[5];
    const float* Wv   = (const float*)d_in[6];
    const float* Wo   = (const float*)d_in[7];
    float* out = (float*)d_out;

    const size_t M  = (size_t)BB * SEQ;   // 4096
    const size_t nX = M * DIN;            // 8,388,608

    char* ws = (char*)d_ws;
    half_t* xh   = (half_t*)(ws);                          // 16 MiB
    half_t* WqT  = (half_t*)(ws + (size_t)(16) * 1048576); //  8 MiB
    half_t* WkT  = (half_t*)(ws + (size_t)(24) * 1048576); //  2 MiB
    half_t* WvT  = (half_t*)(ws + (size_t)(26) * 1048576); //  2 MiB
    half_t* WoT  = (half_t*)(ws + (size_t)(28) * 1048576); //  8 MiB
    float*  Qf   = (float* )(ws + (size_t)(36) * 1048576); // 32 MiB
    float*  KVf  = (float* )(ws + (size_t)(68) * 1048576); //  8 MiB (K then V fp32)
    half_t* Qh   = (half_t*)(ws + (size_t)(76) * 1048576); // 16 MiB
    half_t* Kh   = (half_t*)(ws + (size_t)(92) * 1048576); //  4 MiB
    half_t* Vt   = (half_t*)(ws + (size_t)(96) * 1048576); //  4 MiB
    half_t* ctxh = (half_t*)(ws + (size_t)(36) * 1048576); // alias Qf (dead after rope_q)

    // casts / transposes
    cast_f2h<<<(nX / 4) / 256, 256, 0, stream>>>(x, xh, nX / 4);
    tcast<<<dim3(DOUT / 32, DIN / 32), 256, 0, stream>>>(Wq, WqT, DIN, DOUT);
    tcast<<<dim3((NKV * HD) / 32, DIN / 32), 256, 0, stream>>>(Wk, WkT, DIN, NKV * HD);
    tcast<<<dim3((NKV * HD) / 32, DIN / 32), 256, 0, stream>>>(Wv, WvT, DIN, NKV * HD);
    tcast<<<dim3(DOUT / 32, DOUT / 32), 256, 0, stream>>>(Wo, WoT, DOUT, DOUT);

    // K path (KVf reused for K then V)
    gemm_tn<<<dim3((NKV * HD) / 128, M / 128), 256, 0, stream>>>(xh, WkT, KVf, M, NKV * HD, DIN);
    rope_k<<<(BB * SEQ * NKV * 32) / 256, 256, 0, stream>>>(KVf, cosb, sinb, Kh);
    // V path
    gemm_tn<<<dim3((NKV * HD) / 128, M / 128), 256, 0, stream>>>(xh, WvT, KVf, M, NKV * HD, DIN);
    v_transpose<<<dim3(SEQ / 64, BB * NKV), 256, 0, stream>>>(KVf, Vt);
    // Q path
    gemm_tn<<<dim3(DOUT / 128, M / 128), 256, 0, stream>>>(xh, WqT, Qf, M, DOUT, DIN);
    rope_q<<<(BB * SEQ * NH * 32) / 256, 256, 0, stream>>>(Qf, cosb, sinb, Qh);

    // attention
    attn<<<BB * NH * (SEQ / 128), 256, 0, stream>>>(Qh, Kh, Vt, ctxh);

    // output projection
    gemm_tn<<<dim3(DOUT / 128, M / 128), 256, 0, stream>>>(ctxh, WoT, out, M, DOUT, DIN);
}

// Round 4
// 360.798 us; speedup vs baseline: 2.7704x; 1.7159x over previous
//
#include <hip/hip_runtime.h>
#include <hip/hip_fp16.h>

#define SEQ    2048
#define DIN    2048
#define DOUT   2048
#define NH     32
#define NKV    8
#define HD     64
#define BB     2

typedef _Float16 half_t;
typedef __attribute__((ext_vector_type(8))) _Float16 half8;
typedef __attribute__((ext_vector_type(4))) _Float16 half4;
typedef __attribute__((ext_vector_type(2))) __fp16   fp16x2;   // cvt_pkrtz native type
typedef __attribute__((ext_vector_type(4))) float    floatx4;

union H8U { half8 h; int u[4]; };
union H2I { fp16x2 h; int i; };

// async 16B global->LDS (wave-uniform LDS base + lane*16)
__device__ __forceinline__ void gload16(void* l, const void* g) {
    __builtin_amdgcn_global_load_lds(
        (const __attribute__((address_space(1))) void*)g,
        (__attribute__((address_space(3))) void*)l, 16, 0, 0);
}

// ---------------------------------------------------------------- cast f32->f16
__global__ void cast_f2h(const float* __restrict__ in, half_t* __restrict__ out, int n4) {
    int i = blockIdx.x * blockDim.x + threadIdx.x;
    if (i < n4) {
        float4 v = ((const float4*)in)[i];
        half4 h;
        h[0] = (half_t)v.x; h[1] = (half_t)v.y; h[2] = (half_t)v.z; h[3] = (half_t)v.w;
        ((half4*)out)[i] = h;
    }
}

// ---------------------------------------------------------------- transpose+cast: f32 [Kd][Nd] -> f16 [Nd][Kd]
__global__ __launch_bounds__(256) void tcast(const float* __restrict__ in, half_t* __restrict__ out,
                                             int Kd, int Nd) {
    __shared__ float T[32][33];
    int x0 = blockIdx.x * 32, y0 = blockIdx.y * 32;
    int tx = threadIdx.x & 31, ty = threadIdx.x >> 5;
    #pragma unroll
    for (int j = 0; j < 4; j++)
        T[ty + j * 8][tx] = in[(size_t)(y0 + ty + j * 8) * Nd + x0 + tx];
    __syncthreads();
    #pragma unroll
    for (int j = 0; j < 4; j++)
        out[(size_t)(x0 + ty + j * 8) * Kd + y0 + tx] = (half_t)T[tx][ty + j * 8];
}

// ---------------------------------------------------------------- GEMM (m97 structure), f16 out
// C(MxN) = A(f16,MxK) @ Bt(f16,NxK)^T ; 256 thr, tile 128x128, BK=32, global_load_lds.
__global__ __launch_bounds__(256) void gemm_tn_h(
    const half_t* __restrict__ A, const half_t* __restrict__ Bt,
    half_t* __restrict__ C, int M, int N, int K)
{
    __shared__ half_t As[4096];
    __shared__ half_t Bs[4096];
    int tid = threadIdx.x, wave = tid >> 6, lane = tid & 63;
    int quad = lane >> 4, l15 = lane & 15;
    int m0 = blockIdx.y * 128, n0 = blockIdx.x * 128;
    int wm = (wave >> 1) * 64, wn = (wave & 1) * 64;
    floatx4 acc[4][4] = {};

    int srow[2], skoff[2], sldso[2];
    #pragma unroll
    for (int is = 0; is < 2; is++) {
        int s = is * 256 + tid;
        int p = s >> 3, sc = s & 7;
        int c = sc ^ (p & 7);
        srow[is]  = 2 * p + (c >> 2);
        skoff[is] = (c & 3) * 8;
        sldso[is] = (is * 256 + wave * 64) * 8;
    }
    for (int k0 = 0; k0 < K; k0 += 32) {
        __syncthreads();
        #pragma unroll
        for (int is = 0; is < 2; is++) {
            gload16(&As[sldso[is]], A  + (size_t)(m0 + srow[is]) * K + k0 + skoff[is]);
            gload16(&Bs[sldso[is]], Bt + (size_t)(n0 + srow[is]) * K + k0 + skoff[is]);
        }
        __syncthreads();
        half8 af[4], bf[4];
        #pragma unroll
        for (int i = 0; i < 4; i++) {
            int r = wm + i * 16 + l15, p = r >> 1;
            int sc = (((r & 1) * 4 + quad) ^ (p & 7));
            af[i] = *(const half8*)&As[p * 64 + sc * 8];
            int rn = wn + i * 16 + l15, pn = rn >> 1;
            int scn = (((rn & 1) * 4 + quad) ^ (pn & 7));
            bf[i] = *(const half8*)&Bs[pn * 64 + scn * 8];
        }
        #pragma unroll
        for (int i = 0; i < 4; i++)
            #pragma unroll
            for (int j = 0; j < 4; j++)
                acc[i][j] = __builtin_amdgcn_mfma_f32_16x16x32_f16(af[i], bf[j], acc[i][j], 0, 0, 0);
    }
    #pragma unroll
    for (int i = 0; i < 4; i++) {
        int row = m0 + wm + i * 16 + quad * 4;
        #pragma unroll
        for (int j = 0; j < 4; j++) {
            int col = n0 + wn + j * 16 + l15;
            #pragma unroll
            for (int r = 0; r < 4; r++)
                C[(size_t)(row + r) * N + col] = (half_t)acc[i][j][r];
        }
    }
}

// same, f32 out (final projection)
__global__ __launch_bounds__(256) void gemm_tn_f(
    const half_t* __restrict__ A, const half_t* __restrict__ Bt,
    float* __restrict__ C, int M, int N, int K)
{
    __shared__ half_t As[4096];
    __shared__ half_t Bs[4096];
    int tid = threadIdx.x, wave = tid >> 6, lane = tid & 63;
    int quad = lane >> 4, l15 = lane & 15;
    int m0 = blockIdx.y * 128, n0 = blockIdx.x * 128;
    int wm = (wave >> 1) * 64, wn = (wave & 1) * 64;
    floatx4 acc[4][4] = {};
    int srow[2], skoff[2], sldso[2];
    #pragma unroll
    for (int is = 0; is < 2; is++) {
        int s = is * 256 + tid;
        int p = s >> 3, sc = s & 7;
        int c = sc ^ (p & 7);
        srow[is]  = 2 * p + (c >> 2);
        skoff[is] = (c & 3) * 8;
        sldso[is] = (is * 256 + wave * 64) * 8;
    }
    for (int k0 = 0; k0 < K; k0 += 32) {
        __syncthreads();
        #pragma unroll
        for (int is = 0; is < 2; is++) {
            gload16(&As[sldso[is]], A  + (size_t)(m0 + srow[is]) * K + k0 + skoff[is]);
            gload16(&Bs[sldso[is]], Bt + (size_t)(n0 + srow[is]) * K + k0 + skoff[is]);
        }
        __syncthreads();
        half8 af[4], bf[4];
        #pragma unroll
        for (int i = 0; i < 4; i++) {
            int r = wm + i * 16 + l15, p = r >> 1;
            int sc = (((r & 1) * 4 + quad) ^ (p & 7));
            af[i] = *(const half8*)&As[p * 64 + sc * 8];
            int rn = wn + i * 16 + l15, pn = rn >> 1;
            int scn = (((rn & 1) * 4 + quad) ^ (pn & 7));
            bf[i] = *(const half8*)&Bs[pn * 64 + scn * 8];
        }
        #pragma unroll
        for (int i = 0; i < 4; i++)
            #pragma unroll
            for (int j = 0; j < 4; j++)
                acc[i][j] = __builtin_amdgcn_mfma_f32_16x16x32_f16(af[i], bf[j], acc[i][j], 0, 0, 0);
    }
    #pragma unroll
    for (int i = 0; i < 4; i++) {
        int row = m0 + wm + i * 16 + quad * 4;
        #pragma unroll
        for (int j = 0; j < 4; j++) {
            int col = n0 + wn + j * 16 + l15;
            #pragma unroll
            for (int r = 0; r < 4; r++)
                C[(size_t)(row + r) * N + col] = acc[i][j][r];
        }
    }
}

// ---------------------------------------------------------------- RoPE from fused qkv (f16 [4096][3072])
// Q: cols h*64.. -> Qh [b][h][s][64], scaled 1/8
__global__ void rope_q(const half_t* __restrict__ qkv, const float* __restrict__ cosb,
                       const float* __restrict__ sinb, half_t* __restrict__ Qh) {
    int idx = blockIdx.x * 256 + threadIdx.x;
    int d = idx & 31, h = (idx >> 5) & 31, s = (idx >> 10) & 2047, b = idx >> 21;
    const half_t* q = qkv + (size_t)(b * 2048 + s) * 3072 + h * 64;
    float x1 = (float)q[d], x2 = (float)q[d + 32];
    float c1 = cosb[s * 64 + d], c2 = cosb[s * 64 + d + 32];
    float s1 = sinb[s * 64 + d], s2 = sinb[s * 64 + d + 32];
    half_t* o = Qh + ((size_t)(b * NH + h) * 2048 + s) * 64;
    o[d]      = (half_t)((x1 * c1 - x2 * s1) * 0.125f);
    o[d + 32] = (half_t)((x2 * c2 + x1 * s2) * 0.125f);
}

// K: cols 2048+g*64 -> Kh [b][g][s][64]
__global__ void rope_k(const half_t* __restrict__ qkv, const float* __restrict__ cosb,
                       const float* __restrict__ sinb, half_t* __restrict__ Kh) {
    int idx = blockIdx.x * 256 + threadIdx.x;
    int d = idx & 31, g = (idx >> 5) & 7, s = (idx >> 8) & 2047, b = idx >> 19;
    const half_t* k = qkv + (size_t)(b * 2048 + s) * 3072 + 2048 + g * 64;
    float x1 = (float)k[d], x2 = (float)k[d + 32];
    float c1 = cosb[s * 64 + d], c2 = cosb[s * 64 + d + 32];
    float s1 = sinb[s * 64 + d], s2 = sinb[s * 64 + d + 32];
    half_t* o = Kh + ((size_t)(b * NKV + g) * 2048 + s) * 64;
    o[d]      = (half_t)(x1 * c1 - x2 * s1);
    o[d + 32] = (half_t)(x2 * c2 + x1 * s2);
}

// V: cols 2560+g*64 -> Vt [b][g][64][SEQ]
__global__ __launch_bounds__(256) void v_transpose(const half_t* __restrict__ qkv, half_t* __restrict__ Vt) {
    __shared__ float T[64][65];
    int s0 = blockIdx.x * 64;
    int bg = blockIdx.y; int b = bg >> 3, g = bg & 7;
    int tx = threadIdx.x & 63, ty = threadIdx.x >> 6;
    #pragma unroll
    for (int j = 0; j < 16; j++) {
        int s = ty * 16 + j;
        T[s][tx] = (float)qkv[(size_t)(b * 2048 + s0 + s) * 3072 + 2560 + g * 64 + tx];
    }
    __syncthreads();
    #pragma unroll
    for (int j = 0; j < 16; j++) {
        int d = ty * 16 + j;
        Vt[((size_t)(b * NKV + g) * 64 + d) * SEQ + s0 + tx] = (half_t)T[tx][d];
    }
}

// ---------------------------------------------------------------- causal GQA flash attention (S^T layout)
// 256 thr = 4 waves; 128 queries/block; 64-key tiles, double-buffered async staging.
// mfma(K,Q^T)->S^T: query = lane col -> in-lane softmax; mfma(V^T,P^T)->O^T; P^T built by shuffles.
__global__ __launch_bounds__(256, 4) void attn(
    const half_t* __restrict__ Qh, const half_t* __restrict__ Kh,
    const half_t* __restrict__ Vt, half_t* __restrict__ ctx)
{
    __shared__ half_t Ks[2][4096];
    __shared__ half_t Vs[2][4096];

    const int tid = threadIdx.x, wave = tid >> 6, lane = tid & 63;
    const int quad = lane >> 4, l15 = lane & 15;
    const int bid = blockIdx.x;
    const int qt = 15 - (bid >> 6);      // longest blocks first
    const int b  = (bid >> 5) & 1;
    const int h  = bid & 31;
    const int g  = h >> 2;
    const int q0 = qt * 128;
    const int wm = wave * 32;

    const half_t* kp = Kh + (size_t)(b * NKV + g) * SEQ * 64;
    const half_t* vp = Vt + (size_t)(b * NKV + g) * 64 * SEQ;

    // Q fragments (used as B-operand: n = query = l15)
    half8 qf[2][2];
    {
        const half_t* qpp = Qh + ((size_t)(b * NH + h) * SEQ + q0 + wm) * 64;
        #pragma unroll
        for (int mf = 0; mf < 2; mf++)
            #pragma unroll
            for (int kc = 0; kc < 2; kc++)
                qf[mf][kc] = *(const half8*)(qpp + (size_t)(mf * 16 + l15) * 64 + kc * 32 + quad * 8);
    }

    // staging offsets: seg s -> phys(row p, slot s&7), logical col c = (s&7)^(p&7)
    int koff[2], voff[2], lo[2];
    #pragma unroll
    for (int is = 0; is < 2; is++) {
        int s = is * 256 + tid;
        int p = s >> 3, c = (s & 7) ^ (p & 7);
        koff[is] = p * 64 + c * 8;
        voff[is] = p * SEQ + c * 8;
        lo[is]   = (is * 256 + wave * 64) * 8;
    }

    float m_i[2], l_i[2];
    m_i[0] = m_i[1] = -__builtin_inff();
    l_i[0] = l_i[1] = 0.f;
    floatx4 o[2][4] = {};

    const int ntiles = 2 * qt + 2;
    #pragma unroll
    for (int is = 0; is < 2; is++) {
        gload16(&Ks[0][lo[is]], kp + koff[is]);
        gload16(&Vs[0][lo[is]], vp + voff[is]);
    }

    const int srcA = l15 + ((quad & 1) ? 32 : 0);
    const int srcB = srcA + 16;
    const bool hiK = (quad >> 1) != 0;

    for (int kt = 0; kt < ntiles; kt++) {
        const int cur = kt & 1;
        const int kb  = kt * 64;
        __syncthreads();                       // buf[cur] loads complete (all waves)
        if (kt + 1 < ntiles) {
            const int kb2 = (kt + 1) * 64;
            #pragma unroll
            for (int is = 0; is < 2; is++) {
                gload16(&Ks[cur ^ 1][lo[is]], kp + (size_t)kb2 * 64 + koff[is]);
                gload16(&Vs[cur ^ 1][lo[is]], vp + kb2 + voff[is]);
            }
        }

        if (kb <= q0 + wm + 31) {
            // S^T = K @ Q^T : rows = keys, cols = queries
            floatx4 sa[2][4] = {};
            #pragma unroll
            for (int kc = 0; kc < 2; kc++)
                #pragma unroll
                for (int kf = 0; kf < 4; kf++) {
                    int row = kf * 16 + l15;
                    int sc = ((kc * 4 + quad) ^ (row & 7));
                    half8 kfr = *(const half8*)&Ks[cur][row * 64 + sc * 8];
                    sa[0][kf] = __builtin_amdgcn_mfma_f32_16x16x32_f16(kfr, qf[0][kc], sa[0][kf], 0, 0, 0);
                    sa[1][kf] = __builtin_amdgcn_mfma_f32_16x16x32_f16(kfr, qf[1][kc], sa[1][kf], 0, 0, 0);
                }

            if (kb + 63 > q0 + wm) {   // diagonal tile: mask key > query
                #pragma unroll
                for (int kf = 0; kf < 4; kf++)
                    #pragma unroll
                    for (int r = 0; r < 4; r++) {
                        int key = kb + kf * 16 + quad * 4 + r;
                        if (key > q0 + wm + l15)      sa[0][kf][r] = -__builtin_inff();
                        if (key > q0 + wm + 16 + l15) sa[1][kf][r] = -__builtin_inff();
                    }
            }

            int eh[2][4][2];   // packed half2 exp values
            float alpha[2];
            #pragma unroll
            for (int mf = 0; mf < 2; mf++) {
                float mt = sa[mf][0][0];
                #pragma unroll
                for (int kf = 0; kf < 4; kf++)
                    #pragma unroll
                    for (int r = 0; r < 4; r++) mt = fmaxf(mt, sa[mf][kf][r]);
                mt = fmaxf(mt, __shfl_xor(mt, 16));
                mt = fmaxf(mt, __shfl_xor(mt, 32));
                float mn = fmaxf(m_i[mf], mt);
                alpha[mf] = __expf(m_i[mf] - mn);
                m_i[mf] = mn;
                float rs = 0.f;
                #pragma unroll
                for (int kf = 0; kf < 4; kf++) {
                    float e0 = __expf(sa[mf][kf][0] - mn);
                    float e1 = __expf(sa[mf][kf][1] - mn);
                    float e2 = __expf(sa[mf][kf][2] - mn);
                    float e3 = __expf(sa[mf][kf][3] - mn);
                    rs += (e0 + e1) + (e2 + e3);
                    H2I p01, p23;
                    p01.h = __builtin_amdgcn_cvt_pkrtz(e0, e1);
                    p23.h = __builtin_amdgcn_cvt_pkrtz(e2, e3);
                    eh[mf][kf][0] = p01.i;
                    eh[mf][kf][1] = p23.i;
                }
                rs += __shfl_xor(rs, 16);
                rs += __shfl_xor(rs, 32);
                l_i[mf] = l_i[mf] * alpha[mf] + rs;
                #pragma unroll
                for (int nf = 0; nf < 4; nf++)
                    #pragma unroll
                    for (int r = 0; r < 4; r++) o[mf][nf][r] *= alpha[mf];
            }

            // O^T += V^T @ P^T  (P^T B-frag via in-register shuffles)
            #pragma unroll
            for (int kc = 0; kc < 2; kc++) {
                H8U pf[2];
                #pragma unroll
                for (int mf = 0; mf < 2; mf++) {
                    int a0 = __shfl(eh[mf][2 * kc][0],     srcA);
                    int a1 = __shfl(eh[mf][2 * kc][1],     srcA);
                    int b0 = __shfl(eh[mf][2 * kc + 1][0], srcA);
                    int b1 = __shfl(eh[mf][2 * kc + 1][1], srcA);
                    int c0 = __shfl(eh[mf][2 * kc][0],     srcB);
                    int c1 = __shfl(eh[mf][2 * kc][1],     srcB);
                    int d0 = __shfl(eh[mf][2 * kc + 1][0], srcB);
                    int d1 = __shfl(eh[mf][2 * kc + 1][1], srcB);
                    pf[mf].u[0] = hiK ? b0 : a0;
                    pf[mf].u[1] = hiK ? b1 : a1;
                    pf[mf].u[2] = hiK ? d0 : c0;
                    pf[mf].u[3] = hiK ? d1 : c1;
                }
                #pragma unroll
                for (int nf = 0; nf < 4; nf++) {
                    int row = nf * 16 + l15;
                    int sc = ((kc * 4 + quad) ^ (row & 7));
                    half8 vf = *(const half8*)&Vs[cur][row * 64 + sc * 8];
                    o[0][nf] = __builtin_amdgcn_mfma_f32_16x16x32_f16(vf, pf[0].h, o[0][nf], 0, 0, 0);
                    o[1][nf] = __builtin_amdgcn_mfma_f32_16x16x32_f16(vf, pf[1].h, o[1][nf], 0, 0, 0);
                }
            }
        }
    }

    // epilogue: O^T cols = queries; d = 16nf + 4quad + r -> half4 stores
    #pragma unroll
    for (int mf = 0; mf < 2; mf++) {
        float inv = 1.0f / l_i[mf];
        int s = q0 + wm + mf * 16 + l15;
        half_t* op = ctx + (size_t)(b * SEQ + s) * DOUT + h * 64 + quad * 4;
        #pragma unroll
        for (int nf = 0; nf < 4; nf++) {
            half4 hv;
            hv[0] = (half_t)(o[mf][nf][0] * inv);
            hv[1] = (half_t)(o[mf][nf][1] * inv);
            hv[2] = (half_t)(o[mf][nf][2] * inv);
            hv[3] = (half_t)(o[mf][nf][3] * inv);
            *(half4*)(op + nf * 16) = hv;
        }
    }
}

// ---------------------------------------------------------------- launch
extern "C" void kernel_launch(void* const* d_in, const int* in_sizes, int n_in,
                              void* d_out, int out_size, void* d_ws, size_t ws_size,
                              hipStream_t stream) {
    const float* x    = (const float*)d_in[0];
    const float* cosb = (const float*)d_in[1];
    const float* sinb = (const float*)d_in[2];
    const float* Wq   = (const float*)d_in[4];
    const float* Wk   = (const float*)d_in[5];
    const float* Wv   = (const float*)d_in[6];
    const float* Wo   = (const float*)d_in[7];
    float* out = (float*)d_out;

    const size_t M  = (size_t)BB * SEQ;   // 4096
    const size_t nX = M * DIN;

    char* ws = (char*)d_ws;
    const size_t MB = 1048576;
    half_t* xh     = (half_t*)(ws);              // 16 MiB
    half_t* WqkvT  = (half_t*)(ws + 16 * MB);    // 12 MiB  [3072][2048]
    half_t* WoT    = (half_t*)(ws + 28 * MB);    //  8 MiB
    half_t* qkvh   = (half_t*)(ws + 36 * MB);    // 24 MiB  [4096][3072]
    half_t* Qh     = (half_t*)(ws + 60 * MB);    // 16 MiB
    half_t* Kh     = (half_t*)(ws + 76 * MB);    //  4 MiB
    half_t* Vt     = (half_t*)(ws + 80 * MB);    //  4 MiB
    half_t* ctxh   = (half_t*)(ws + 84 * MB);    // 16 MiB

    // casts / weight transposes (Wq|Wk|Wv fused into one [3072][2048] Bt)
    cast_f2h<<<(nX / 4) / 256, 256, 0, stream>>>(x, xh, nX / 4);
    tcast<<<dim3(64, 64), 256, 0, stream>>>(Wq, WqkvT, DIN, DOUT);
    tcast<<<dim3(16, 64), 256, 0, stream>>>(Wk, WqkvT + (size_t)2048 * 2048, DIN, 512);
    tcast<<<dim3(16, 64), 256, 0, stream>>>(Wv, WqkvT + (size_t)2560 * 2048, DIN, 512);
    tcast<<<dim3(64, 64), 256, 0, stream>>>(Wo, WoT, DOUT, DOUT);

    // fused QKV projection -> qkvh f16 [4096][3072]
    gemm_tn_h<<<dim3(3072 / 128, M / 128), 256, 0, stream>>>(xh, WqkvT, qkvh, M, 3072, DIN);

    // RoPE + relayout
    rope_q<<<(BB * SEQ * NH * 32) / 256, 256, 0, stream>>>(qkvh, cosb, sinb, Qh);
    rope_k<<<(BB * SEQ * NKV * 32) / 256, 256, 0, stream>>>(qkvh, cosb, sinb, Kh);
    v_transpose<<<dim3(SEQ / 64, BB * NKV), 256, 0, stream>>>(qkvh, Vt);

    // attention
    attn<<<BB * NH * (SEQ / 128), 256, 0, stream>>>(Qh, Kh, Vt, ctxh);

    // output projection (f32 out)
    gemm_tn_f<<<dim3(DOUT / 128, M / 128), 256, 0, stream>>>(ctxh, WoT, out, M, DOUT, DIN);
}